// Round 9
// baseline (133.947 us; speedup 1.0000x reference)
//
#include <hip/hip_runtime.h>

#define NN 50000
#define NE 800000
#define ETOT (NE + NN)           // 850000 incl. self-loops
#define INCH 128
#define OUTC 64
#define LOG2E 1.44269504088896f
#define NBK 196                  // dst buckets (dst>>8), 256 nodes each
#define BCAP 5120                // bucket capacity (avg 4352, sigma 64)
#define EPB 1024                 // edges per binA block
#define BTH 1024                 // binB block size

// ---------------- workspace layout (bytes) ----------------
// hbuf  : uint[4][NN][16] @ 0           (12,800,000)  group-major packed bf16
// asrc  : float2[NN]      @ 12,800,000  (400,000)     (pre-scaled by log2e)
// adst  : float2[NN]      @ 13,200,000  (400,000)     (pre-scaled by log2e)
// gbc   : int[NBK]        @ 13,600,000  (1,024)       (memset to 0)
// bbase : int[NBK+1]      @ 13,601,024  (1,024)
// off   : int[NN+1]       @ 13,602,048  (200,004)
// srcs16: ushort[ETOT]    @ 13,802,052  (1,700,000)
// wpk   : uint[ETOT]      @ 15,502,052  (3,400,000)   packed bf16 (w0 lo, w1 hi)
// binb  : uint[NBK*BCAP]  @ 18,902,052  (4,014,080)   s | (d&255)<<16
#define OFF_HBUF  0
#define OFF_ASRC  12800000
#define OFF_ADST  13200000
#define OFF_GBC   13600000
#define OFF_BBASE 13601024
#define OFF_OFF   13602048
#define OFF_SRC16 13802052
#define OFF_WPK   15502052
#define OFF_BINB  18902052

typedef __attribute__((ext_vector_type(8))) short short8v;   // 8 bf16 (4 VGPR)
typedef __attribute__((ext_vector_type(4))) float float4v;   // MFMA acc
typedef unsigned long long ull;

__device__ __forceinline__ unsigned short f2bf(float f) {
    unsigned u = __float_as_uint(f);
    u += 0x7fffu + ((u >> 16) & 1u);   // round-to-nearest-even
    return (unsigned short)(u >> 16);
}
__device__ __forceinline__ unsigned packbf(float a, float b) {
    return (unsigned)f2bf(a) | ((unsigned)f2bf(b) << 16);
}

// ---------------------------------------------------------------------------
// MFMA projection: h = x@W (bf16 in, fp32 acc); hbuf in group-major layout
// [grp][node][16] (64B per node per group); attention dots pre-scaled.
// ---------------------------------------------------------------------------
#define PITCH 272
#define XLDS_BYTES (64 * PITCH)
#define WT_OFF XLDS_BYTES
#define SMEM_BYTES (XLDS_BYTES + 128 * PITCH)  // 52224

__global__ __launch_bounds__(256) void k_proj(const float* __restrict__ x,
                                              const float* __restrict__ W,
                                              const float* __restrict__ att_src,
                                              const float* __restrict__ att_dst,
                                              unsigned* __restrict__ hbuf,
                                              float2* __restrict__ asrc,
                                              float2* __restrict__ adst) {
    __shared__ char smem[SMEM_BYTES];
    const int t = threadIdx.x;
    const int nbase = blockIdx.x * 64;

    // ---- stage x-tile (64 rows x 128 k) as bf16, pitch 272 ----
    {
        const int rl = t >> 2;
        const int q  = t & 3;
        int rg = nbase + rl;
        if (rg >= NN) rg = NN - 1;
        const float4* src = (const float4*)(x + (size_t)rg * INCH + q * 32);
        char* dst = smem + rl * PITCH + q * 64;
#pragma unroll
        for (int i = 0; i < 8; ++i) {
            const float4 v = src[i];
            const unsigned lo = packbf(v.x, v.y);
            const unsigned hi = packbf(v.z, v.w);
            *(ull*)(dst + i * 8) = (ull)lo | ((ull)hi << 32);
        }
    }
    // ---- stage W^T (128 cols x 128 k) as bf16, pitch 272 ----
    {
        const int c  = t & 127;
        const int kh = t >> 7;
        const float* wcol = W + c;
        char* dst = smem + WT_OFF + c * PITCH + kh * 128;
#pragma unroll
        for (int i = 0; i < 16; ++i) {
            const int k = kh * 64 + i * 4;
            const float w0 = wcol[(size_t)(k + 0) * 128];
            const float w1 = wcol[(size_t)(k + 1) * 128];
            const float w2 = wcol[(size_t)(k + 2) * 128];
            const float w3 = wcol[(size_t)(k + 3) * 128];
            const unsigned lo = packbf(w0, w1);
            const unsigned hi = packbf(w2, w3);
            *(ull*)(dst + i * 8) = (ull)lo | ((ull)hi << 32);
        }
    }
    __syncthreads();

    const int w  = t >> 6;
    const int l  = t & 63;
    const int li = l & 15;
    const int g  = l >> 4;

    const char* xb = smem + (w * 16 + li) * PITCH + g * 16;
    const char* wb = smem + WT_OFF + li * PITCH + g * 16;

    float4v acc[8] = {};
#pragma unroll
    for (int ks = 0; ks < 4; ++ks) {
        const short8v aF = *(const short8v*)(xb + ks * 64);
#pragma unroll
        for (int nt = 0; nt < 8; ++nt) {
            const short8v bF = *(const short8v*)(wb + nt * (16 * PITCH) + ks * 64);
            acc[nt] = __builtin_amdgcn_mfma_f32_16x16x32_bf16(aF, bF, acc[nt], 0, 0, 0);
        }
    }

    float aS0[4], aS1[4], aD0[4], aD1[4];
#pragma unroll
    for (int tt = 0; tt < 4; ++tt) {
        aS0[tt] = att_src[tt * 16 + li];
        aS1[tt] = att_src[64 + tt * 16 + li];
        aD0[tt] = att_dst[tt * 16 + li];
        aD1[tt] = att_dst[64 + tt * 16 + li];
    }
#pragma unroll
    for (int r = 0; r < 4; ++r) {
        const int n = nbase + w * 16 + g * 4 + r;
        const bool valid = (n < NN);
        float ps0 = 0.f, ps1 = 0.f, pd0 = 0.f, pd1 = 0.f;
#pragma unroll
        for (int tt = 0; tt < 4; ++tt) {
            const float h0 = acc[tt][r];
            const float h1 = acc[tt + 4][r];
            // group-major: [tt][n][li]
            if (valid) hbuf[((size_t)tt * NN + n) * 16 + li] = packbf(h0, h1);
            ps0 += h0 * aS0[tt];
            ps1 += h1 * aS1[tt];
            pd0 += h0 * aD0[tt];
            pd1 += h1 * aD1[tt];
        }
#pragma unroll
        for (int m = 1; m <= 8; m <<= 1) {
            ps0 += __shfl_xor(ps0, m);
            ps1 += __shfl_xor(ps1, m);
            pd0 += __shfl_xor(pd0, m);
            pd1 += __shfl_xor(pd1, m);
        }
        if (valid && li == 0) {
            asrc[n] = make_float2(ps0 * LOG2E, ps1 * LOG2E);
            adst[n] = make_float2(pd0 * LOG2E, pd1 * LOG2E);
        }
    }
}

// ---------------------------------------------------------------------------
// binA: single pass — edges cached in registers, LDS bucket histogram,
// reserve chunks in gbc, write packed uint (s | dlow<<16) into bucket regions.
// ---------------------------------------------------------------------------
__global__ __launch_bounds__(256) void k_binA(const int* __restrict__ ei,
                                              int* __restrict__ gbc,
                                              unsigned* __restrict__ binb) {
    __shared__ int lcnt[NBK];
    __shared__ int lbase[NBK];
    const int t = threadIdx.x;
    const int e0 = blockIdx.x * EPB;

    for (int i = t; i < NBK; i += 256) lcnt[i] = 0;
    __syncthreads();

    int sr[EPB / 256], dr[EPB / 256];
#pragma unroll
    for (int k = 0; k < EPB / 256; ++k) {
        const int e = e0 + k * 256 + t;
        if (e < ETOT) {
            int s, d;
            if (e < NE) { s = ei[e]; d = ei[NE + e]; }
            else        { s = d = e - NE; }
            sr[k] = s; dr[k] = d;
            atomicAdd(&lcnt[d >> 8], 1);
        } else {
            sr[k] = -1; dr[k] = 0;
        }
    }
    __syncthreads();
    for (int i = t; i < NBK; i += 256) {
        const int c = lcnt[i];
        lbase[i] = c ? atomicAdd(&gbc[i], c) : 0;
        lcnt[i] = 0;
    }
    __syncthreads();
#pragma unroll
    for (int k = 0; k < EPB / 256; ++k) {
        if (sr[k] >= 0) {
            const int b = dr[k] >> 8;
            const int r = lbase[b] + atomicAdd(&lcnt[b], 1);
            if (r < BCAP)
                binb[(size_t)b * BCAP + r] =
                    (unsigned)sr[k] | ((unsigned)(dr[k] & 255) << 16);
        }
    }
}

// exclusive scan of gbc[NBK] -> bbase[0..NBK]; off[NN] = ETOT
__global__ __launch_bounds__(256) void k_bscan(const int* __restrict__ gbc,
                                               int* __restrict__ bbase,
                                               int* __restrict__ off_last) {
    const int t = threadIdx.x;
    const int v = (t < NBK) ? gbc[t] : 0;
    int incl = v;
#pragma unroll
    for (int o = 1; o < 64; o <<= 1) {
        int u = __shfl_up(incl, o);
        if ((t & 63) >= o) incl += u;
    }
    __shared__ int ws[4], wsx[4];
    if ((t & 63) == 63) ws[t >> 6] = incl;
    __syncthreads();
    if (t == 0) {
        int r = 0;
#pragma unroll
        for (int i = 0; i < 4; ++i) { wsx[i] = r; r += ws[i]; }
        bbase[NBK] = r;
        off_last[0] = r;            // == ETOT
    }
    __syncthreads();
    if (t < NBK) bbase[t] = incl - v + wsx[t >> 6];
}

// ---------------------------------------------------------------------------
// binB: one block per bucket. LDS per-node histogram + 256-scan -> off,
// then place srcs16/wpk into the bucket's contiguous CSR window.
// ---------------------------------------------------------------------------
__global__ __launch_bounds__(BTH) void k_binB(const unsigned* __restrict__ binb,
                                              const int* __restrict__ gbc,
                                              const int* __restrict__ bbase,
                                              const float2* __restrict__ asrc,
                                              const float2* __restrict__ adst,
                                              int* __restrict__ off,
                                              unsigned short* __restrict__ srcs16,
                                              unsigned* __restrict__ wpk) {
    __shared__ int lcnt[256];
    __shared__ int lcur[256];
    __shared__ int ws[4], wsx[4];
    const int b = blockIdx.x;
    const int t = threadIdx.x;
    int n = gbc[b];
    if (n > BCAP) n = BCAP;
    const int base = bbase[b];
    const unsigned* bb = binb + (size_t)b * BCAP;

    if (t < 256) lcnt[t] = 0;
    __syncthreads();

    for (int i = t; i < n; i += BTH)
        atomicAdd(&lcnt[(bb[i] >> 16) & 255], 1);
    __syncthreads();

    // 256-wide exclusive scan (first 4 waves)
    int v = 0, incl = 0;
    if (t < 256) {
        v = lcnt[t];
        incl = v;
#pragma unroll
        for (int o = 1; o < 64; o <<= 1) {
            int u = __shfl_up(incl, o);
            if ((t & 63) >= o) incl += u;
        }
        if ((t & 63) == 63) ws[t >> 6] = incl;
    }
    __syncthreads();
    if (t == 0) {
        int r = 0;
#pragma unroll
        for (int i = 0; i < 4; ++i) { wsx[i] = r; r += ws[i]; }
    }
    __syncthreads();
    if (t < 256) {
        const int excl = incl - v + wsx[t >> 6];
        lcur[t] = excl;
        const int nd = b * 256 + t;
        if (nd < NN) off[nd] = base + excl;
    }
    __syncthreads();

    for (int i = t; i < n; i += BTH) {
        const unsigned pk = bb[i];
        const int s    = (int)(pk & 0xffffu);
        const int dlow = (int)((pk >> 16) & 255);
        const int pos  = base + atomicAdd(&lcur[dlow], 1);
        const float2 as = asrc[s];
        const float2 ad = adst[b * 256 + dlow];
        float v0 = as.x + ad.x;
        float v1 = as.y + ad.y;
        v0 = v0 > 0.f ? v0 : 0.2f * v0;
        v1 = v1 > 0.f ? v1 : 0.2f * v1;
        srcs16[pos] = (unsigned short)s;
        wpk[pos] = packbf(exp2f(v0), exp2f(v1));
    }
}

// ---------------------------------------------------------------------------
// agg pass: one wave per node, ONE 16-channel group (64B/node working set
// = 3.2MB -> L2-resident). Lane = eg*16+li: 4 edges in parallel (eg), lane
// handles channel li. 4x unroll -> 16 cache lines in flight. Tail masked
// by clamped index + zero weight (no serial tail).
// hbufG/bias/out pre-offset by the group (16 channels) at launch.
// ---------------------------------------------------------------------------
__global__ __launch_bounds__(256) void k_aggp(const int* __restrict__ off,
                                              const unsigned short* __restrict__ srcs16,
                                              const unsigned* __restrict__ wpk,
                                              const unsigned* __restrict__ hbufG,
                                              const float* __restrict__ biasG,
                                              float* __restrict__ outG) {
    const int wid = (int)((blockIdx.x * 256 + threadIdx.x) >> 6);
    const int lane = threadIdx.x & 63;
    if (wid >= NN) return;
    const int eg = lane >> 4;
    const int li = lane & 15;
    const int beg = off[wid];
    const int end = off[wid + 1];

    float acc0 = 0.f, acc1 = 0.f, D0 = 0.f, D1 = 0.f;

    for (int i = beg; i < end; i += 16) {
#pragma unroll
        for (int j = 0; j < 4; ++j) {
            const int e  = i + j * 4 + eg;
            const int ec = e < end ? e : end - 1;       // clamp (hot line)
            const unsigned s  = srcs16[ec];
            const unsigned wv = wpk[ec];
            const unsigned pk = hbufG[s * 16 + li];     // one 64B line / edge
            float w0 = __uint_as_float(wv << 16);
            float w1 = __uint_as_float(wv & 0xffff0000u);
            if (e >= end) { w0 = 0.f; w1 = 0.f; }       // mask tail
            acc0 += w0 * __uint_as_float(pk << 16);
            acc1 += w1 * __uint_as_float(pk & 0xffff0000u);
            D0 += w0;
            D1 += w1;
        }
    }

    // combine the 4 edge-subgroups (lanes with same li)
    acc0 += __shfl_xor(acc0, 16); acc0 += __shfl_xor(acc0, 32);
    acc1 += __shfl_xor(acc1, 16); acc1 += __shfl_xor(acc1, 32);
    D0   += __shfl_xor(D0, 16);   D0   += __shfl_xor(D0, 32);
    D1   += __shfl_xor(D1, 16);   D1   += __shfl_xor(D1, 32);

    if (lane < 16)
        outG[(size_t)wid * 64 + li] = biasG[li] + 0.5f * (acc0 / D0 + acc1 / D1);
}

extern "C" void kernel_launch(void* const* d_in, const int* in_sizes, int n_in,
                              void* d_out, int out_size, void* d_ws, size_t ws_size,
                              hipStream_t stream) {
    const float* x       = (const float*)d_in[0];
    const float* W       = (const float*)d_in[1];
    const float* att_src = (const float*)d_in[2];
    const float* att_dst = (const float*)d_in[3];
    const float* bias    = (const float*)d_in[4];
    const int*   ei      = (const int*)d_in[5];
    float* out = (float*)d_out;

    char* ws = (char*)d_ws;
    unsigned*       hbuf   = (unsigned*)(ws + OFF_HBUF);
    float2*         asrc   = (float2*)(ws + OFF_ASRC);
    float2*         adst   = (float2*)(ws + OFF_ADST);
    int*            gbc    = (int*)(ws + OFF_GBC);
    int*            bbase  = (int*)(ws + OFF_BBASE);
    int*            off    = (int*)(ws + OFF_OFF);
    unsigned short* srcs16 = (unsigned short*)(ws + OFF_SRC16);
    unsigned*       wpk    = (unsigned*)(ws + OFF_WPK);
    unsigned*       binb   = (unsigned*)(ws + OFF_BINB);

    hipMemsetAsync(gbc, 0, 1024, stream);

    k_proj<<<(NN + 63) / 64, 256, 0, stream>>>(x, W, att_src, att_dst, hbuf, asrc, adst);
    k_binA<<<(ETOT + EPB - 1) / EPB, 256, 0, stream>>>(ei, gbc, binb);
    k_bscan<<<1, 256, 0, stream>>>(gbc, bbase, off + NN);
    k_binB<<<NBK, BTH, 0, stream>>>(binb, gbc, bbase, asrc, adst, off, srcs16, wpk);
    // 4 channel-group passes; each gather working set = 3.2MB (L2-resident)
    for (int p = 0; p < 4; ++p) {
        k_aggp<<<(NN * 64 + 255) / 256, 256, 0, stream>>>(
            off, srcs16, wpk,
            hbuf + (size_t)p * NN * 16,
            bias + p * 16,
            out + p * 16);
    }
}

// Round 10
// 92.224 us; speedup vs baseline: 1.4524x; 1.4524x over previous
//
#include <hip/hip_runtime.h>

#define NN 50000
#define NE 800000
#define ETOT (NE + NN)           // 850000 incl. self-loops
#define INCH 128
#define OUTC 64
#define LOG2E 1.44269504088896f
#define NBK 196                  // dst buckets (dst>>8), 256 nodes each
#define BCAP 5120                // bucket capacity (avg 4352, sigma 64)
#define EPB 1024                 // edges per binA block
#define BTH 1024                 // binB block size

// ---------------- workspace layout (bytes) ----------------
// hbuf  : uint[NN*64]     @ 0           (12,800,000)  packed bf16 (h0 lo, h1 hi)
// asrc  : float2[NN]      @ 12,800,000  (400,000)     (pre-scaled by log2e)
// adst  : float2[NN]      @ 13,200,000  (400,000)     (pre-scaled by log2e)
// gbc   : int[NBK]        @ 13,600,000  (1,024)       (zeroed by k_proj blk 0)
// bbase : int[NBK+1]      @ 13,601,024  (1,024)
// off   : int[NN+1]       @ 13,602,048  (200,004)
// srcs16: ushort[ETOT]    @ 13,802,052  (1,700,000)
// wpk   : uint[ETOT]      @ 15,502,052  (3,400,000)   packed bf16 (w0 lo, w1 hi)
// binb  : uint[NBK*BCAP]  @ 18,902,052  (4,014,080)   s | (d&255)<<16
#define OFF_HBUF  0
#define OFF_ASRC  12800000
#define OFF_ADST  13200000
#define OFF_GBC   13600000
#define OFF_BBASE 13601024
#define OFF_OFF   13602048
#define OFF_SRC16 13802052
#define OFF_WPK   15502052
#define OFF_BINB  18902052

typedef __attribute__((ext_vector_type(8))) short short8v;   // 8 bf16 (4 VGPR)
typedef __attribute__((ext_vector_type(4))) float float4v;   // MFMA acc
typedef unsigned long long ull;

__device__ __forceinline__ unsigned short f2bf(float f) {
    unsigned u = __float_as_uint(f);
    u += 0x7fffu + ((u >> 16) & 1u);   // round-to-nearest-even
    return (unsigned short)(u >> 16);
}
__device__ __forceinline__ unsigned packbf(float a, float b) {
    return (unsigned)f2bf(a) | ((unsigned)f2bf(b) << 16);
}

// ---------------------------------------------------------------------------
// MFMA projection: h = x@W (bf16 in, fp32 acc), packed bf16 hbuf out
// (interleaved [node][64ch]), attention dots pre-scaled by log2e.
// Block 0 also zeroes gbc (replaces the 42us fillBufferAligned memset).
// ---------------------------------------------------------------------------
#define PITCH 272
#define XLDS_BYTES (64 * PITCH)
#define WT_OFF XLDS_BYTES
#define SMEM_BYTES (XLDS_BYTES + 128 * PITCH)  // 52224

__global__ __launch_bounds__(256) void k_proj(const float* __restrict__ x,
                                              const float* __restrict__ W,
                                              const float* __restrict__ att_src,
                                              const float* __restrict__ att_dst,
                                              unsigned* __restrict__ hbuf,
                                              float2* __restrict__ asrc,
                                              float2* __restrict__ adst,
                                              int* __restrict__ gbc) {
    __shared__ char smem[SMEM_BYTES];
    const int t = threadIdx.x;
    const int nbase = blockIdx.x * 64;

    // zero the bucket counters (1 block is enough; k_binA runs after k_proj)
    if (blockIdx.x == 0 && t < NBK) gbc[t] = 0;

    // ---- stage x-tile (64 rows x 128 k) as bf16, pitch 272 ----
    {
        const int rl = t >> 2;
        const int q  = t & 3;
        int rg = nbase + rl;
        if (rg >= NN) rg = NN - 1;
        const float4* src = (const float4*)(x + (size_t)rg * INCH + q * 32);
        char* dst = smem + rl * PITCH + q * 64;
#pragma unroll
        for (int i = 0; i < 8; ++i) {
            const float4 v = src[i];
            const unsigned lo = packbf(v.x, v.y);
            const unsigned hi = packbf(v.z, v.w);
            *(ull*)(dst + i * 8) = (ull)lo | ((ull)hi << 32);
        }
    }
    // ---- stage W^T (128 cols x 128 k) as bf16, pitch 272 ----
    {
        const int c  = t & 127;
        const int kh = t >> 7;
        const float* wcol = W + c;
        char* dst = smem + WT_OFF + c * PITCH + kh * 128;
#pragma unroll
        for (int i = 0; i < 16; ++i) {
            const int k = kh * 64 + i * 4;
            const float w0 = wcol[(size_t)(k + 0) * 128];
            const float w1 = wcol[(size_t)(k + 1) * 128];
            const float w2 = wcol[(size_t)(k + 2) * 128];
            const float w3 = wcol[(size_t)(k + 3) * 128];
            const unsigned lo = packbf(w0, w1);
            const unsigned hi = packbf(w2, w3);
            *(ull*)(dst + i * 8) = (ull)lo | ((ull)hi << 32);
        }
    }
    __syncthreads();

    const int w  = t >> 6;
    const int l  = t & 63;
    const int li = l & 15;
    const int g  = l >> 4;

    const char* xb = smem + (w * 16 + li) * PITCH + g * 16;
    const char* wb = smem + WT_OFF + li * PITCH + g * 16;

    float4v acc[8] = {};
#pragma unroll
    for (int ks = 0; ks < 4; ++ks) {
        const short8v aF = *(const short8v*)(xb + ks * 64);
#pragma unroll
        for (int nt = 0; nt < 8; ++nt) {
            const short8v bF = *(const short8v*)(wb + nt * (16 * PITCH) + ks * 64);
            acc[nt] = __builtin_amdgcn_mfma_f32_16x16x32_bf16(aF, bF, acc[nt], 0, 0, 0);
        }
    }

    float aS0[4], aS1[4], aD0[4], aD1[4];
#pragma unroll
    for (int tt = 0; tt < 4; ++tt) {
        aS0[tt] = att_src[tt * 16 + li];
        aS1[tt] = att_src[64 + tt * 16 + li];
        aD0[tt] = att_dst[tt * 16 + li];
        aD1[tt] = att_dst[64 + tt * 16 + li];
    }
#pragma unroll
    for (int r = 0; r < 4; ++r) {
        const int n = nbase + w * 16 + g * 4 + r;
        const bool valid = (n < NN);
        float ps0 = 0.f, ps1 = 0.f, pd0 = 0.f, pd1 = 0.f;
#pragma unroll
        for (int tt = 0; tt < 4; ++tt) {
            const float h0 = acc[tt][r];
            const float h1 = acc[tt + 4][r];
            if (valid) hbuf[(size_t)n * 64 + tt * 16 + li] = packbf(h0, h1);
            ps0 += h0 * aS0[tt];
            ps1 += h1 * aS1[tt];
            pd0 += h0 * aD0[tt];
            pd1 += h1 * aD1[tt];
        }
#pragma unroll
        for (int m = 1; m <= 8; m <<= 1) {
            ps0 += __shfl_xor(ps0, m);
            ps1 += __shfl_xor(ps1, m);
            pd0 += __shfl_xor(pd0, m);
            pd1 += __shfl_xor(pd1, m);
        }
        if (valid && li == 0) {
            asrc[n] = make_float2(ps0 * LOG2E, ps1 * LOG2E);
            adst[n] = make_float2(pd0 * LOG2E, pd1 * LOG2E);
        }
    }
}

// ---------------------------------------------------------------------------
// binA: single pass — edges cached in registers, LDS bucket histogram,
// reserve chunks in gbc, write packed uint (s | dlow<<16) into bucket regions.
// ---------------------------------------------------------------------------
__global__ __launch_bounds__(256) void k_binA(const int* __restrict__ ei,
                                              int* __restrict__ gbc,
                                              unsigned* __restrict__ binb) {
    __shared__ int lcnt[NBK];
    __shared__ int lbase[NBK];
    const int t = threadIdx.x;
    const int e0 = blockIdx.x * EPB;

    for (int i = t; i < NBK; i += 256) lcnt[i] = 0;
    __syncthreads();

    int sr[EPB / 256], dr[EPB / 256];
#pragma unroll
    for (int k = 0; k < EPB / 256; ++k) {
        const int e = e0 + k * 256 + t;
        if (e < ETOT) {
            int s, d;
            if (e < NE) { s = ei[e]; d = ei[NE + e]; }
            else        { s = d = e - NE; }
            sr[k] = s; dr[k] = d;
            atomicAdd(&lcnt[d >> 8], 1);
        } else {
            sr[k] = -1; dr[k] = 0;
        }
    }
    __syncthreads();
    for (int i = t; i < NBK; i += 256) {
        const int c = lcnt[i];
        lbase[i] = c ? atomicAdd(&gbc[i], c) : 0;
        lcnt[i] = 0;
    }
    __syncthreads();
#pragma unroll
    for (int k = 0; k < EPB / 256; ++k) {
        if (sr[k] >= 0) {
            const int b = dr[k] >> 8;
            const int r = lbase[b] + atomicAdd(&lcnt[b], 1);
            if (r < BCAP)
                binb[(size_t)b * BCAP + r] =
                    (unsigned)sr[k] | ((unsigned)(dr[k] & 255) << 16);
        }
    }
}

// exclusive scan of gbc[NBK] -> bbase[0..NBK]; off[NN] = ETOT
__global__ __launch_bounds__(256) void k_bscan(const int* __restrict__ gbc,
                                               int* __restrict__ bbase,
                                               int* __restrict__ off_last) {
    const int t = threadIdx.x;
    const int v = (t < NBK) ? gbc[t] : 0;
    int incl = v;
#pragma unroll
    for (int o = 1; o < 64; o <<= 1) {
        int u = __shfl_up(incl, o);
        if ((t & 63) >= o) incl += u;
    }
    __shared__ int ws[4], wsx[4];
    if ((t & 63) == 63) ws[t >> 6] = incl;
    __syncthreads();
    if (t == 0) {
        int r = 0;
#pragma unroll
        for (int i = 0; i < 4; ++i) { wsx[i] = r; r += ws[i]; }
        bbase[NBK] = r;
        off_last[0] = r;            // == ETOT
    }
    __syncthreads();
    if (t < NBK) bbase[t] = incl - v + wsx[t >> 6];
}

// ---------------------------------------------------------------------------
// binB: one block per bucket. LDS per-node histogram + 256-scan -> off,
// then place srcs16/wpk into the bucket's contiguous CSR window.
// ---------------------------------------------------------------------------
__global__ __launch_bounds__(BTH) void k_binB(const unsigned* __restrict__ binb,
                                              const int* __restrict__ gbc,
                                              const int* __restrict__ bbase,
                                              const float2* __restrict__ asrc,
                                              const float2* __restrict__ adst,
                                              int* __restrict__ off,
                                              unsigned short* __restrict__ srcs16,
                                              unsigned* __restrict__ wpk) {
    __shared__ int lcnt[256];
    __shared__ int lcur[256];
    __shared__ int ws[4], wsx[4];
    const int b = blockIdx.x;
    const int t = threadIdx.x;
    int n = gbc[b];
    if (n > BCAP) n = BCAP;
    const int base = bbase[b];
    const unsigned* bb = binb + (size_t)b * BCAP;

    if (t < 256) lcnt[t] = 0;
    __syncthreads();

    for (int i = t; i < n; i += BTH)
        atomicAdd(&lcnt[(bb[i] >> 16) & 255], 1);
    __syncthreads();

    // 256-wide exclusive scan (first 4 waves)
    int v = 0, incl = 0;
    if (t < 256) {
        v = lcnt[t];
        incl = v;
#pragma unroll
        for (int o = 1; o < 64; o <<= 1) {
            int u = __shfl_up(incl, o);
            if ((t & 63) >= o) incl += u;
        }
        if ((t & 63) == 63) ws[t >> 6] = incl;
    }
    __syncthreads();
    if (t == 0) {
        int r = 0;
#pragma unroll
        for (int i = 0; i < 4; ++i) { wsx[i] = r; r += ws[i]; }
    }
    __syncthreads();
    if (t < 256) {
        const int excl = incl - v + wsx[t >> 6];
        lcur[t] = excl;
        const int nd = b * 256 + t;
        if (nd < NN) off[nd] = base + excl;
    }
    __syncthreads();

    for (int i = t; i < n; i += BTH) {
        const unsigned pk = bb[i];
        const int s    = (int)(pk & 0xffffu);
        const int dlow = (int)((pk >> 16) & 255);
        const int pos  = base + atomicAdd(&lcur[dlow], 1);
        const float2 as = asrc[s];
        const float2 ad = adst[b * 256 + dlow];
        float v0 = as.x + ad.x;
        float v1 = as.y + ad.y;
        v0 = v0 > 0.f ? v0 : 0.2f * v0;
        v1 = v1 > 0.f ? v1 : 0.2f * v1;
        srcs16[pos] = (unsigned short)s;
        wpk[pos] = packbf(exp2f(v0), exp2f(v1));
    }
}

// ---------------------------------------------------------------------------
// agg: one 64-lane wave per node; each half-wave (32 lanes, uint2 = 2 channels
// per lane) processes a different edge-parity -> with the 8-wide unroll,
// 16 independent gather chains per wave. Tail is clamp+masked (no serial tail).
// ---------------------------------------------------------------------------
__global__ __launch_bounds__(256) void k_agg(const int* __restrict__ off,
                                             const unsigned short* __restrict__ srcs16,
                                             const unsigned* __restrict__ wpk,
                                             const uint2* __restrict__ hbuf2,
                                             const float2* __restrict__ bias2,
                                             float2* __restrict__ out2) {
    const int wid = (int)((blockIdx.x * 256 + threadIdx.x) >> 6);
    const int lane = threadIdx.x & 63;
    if (wid >= NN) return;
    const int half = lane >> 5;          // edge-parity this lane serves
    const int sl   = lane & 31;          // channel pair index
    const int beg = off[wid];
    const int end = off[wid + 1];

    float a0x = 0.f, a1x = 0.f, a0y = 0.f, a1y = 0.f, D0 = 0.f, D1 = 0.f;

    for (int i = beg + half; i < end; i += 16) {
        unsigned s[8], w[8];
        uint2 p[8];
        int e[8];
#pragma unroll
        for (int j = 0; j < 8; ++j) {
            e[j] = i + 2 * j;
            const int ec = e[j] < end ? e[j] : end - 1;   // clamp (hot line)
            s[j] = srcs16[ec];
        }
#pragma unroll
        for (int j = 0; j < 8; ++j) p[j] = hbuf2[(s[j] << 5) | sl];
#pragma unroll
        for (int j = 0; j < 8; ++j) {
            const int ec = e[j] < end ? e[j] : end - 1;
            w[j] = wpk[ec];
            if (e[j] >= end) w[j] = 0;                    // mask tail
        }
#pragma unroll
        for (int j = 0; j < 8; ++j) {
            const float w0 = __uint_as_float(w[j] << 16);
            const float w1 = __uint_as_float(w[j] & 0xffff0000u);
            a0x += w0 * __uint_as_float(p[j].x << 16);
            a1x += w1 * __uint_as_float(p[j].x & 0xffff0000u);
            a0y += w0 * __uint_as_float(p[j].y << 16);
            a1y += w1 * __uint_as_float(p[j].y & 0xffff0000u);
            D0 += w0;
            D1 += w1;
        }
    }

    // combine the two edge-parity halves (lane l <-> l^32 hold same channels)
    a0x += __shfl_xor(a0x, 32);
    a1x += __shfl_xor(a1x, 32);
    a0y += __shfl_xor(a0y, 32);
    a1y += __shfl_xor(a1y, 32);
    D0  += __shfl_xor(D0, 32);
    D1  += __shfl_xor(D1, 32);

    if (half == 0) {
        const float2 bv = bias2[sl];
        out2[(size_t)wid * 32 + sl] =
            make_float2(bv.x + 0.5f * (a0x / D0 + a1x / D1),
                        bv.y + 0.5f * (a0y / D0 + a1y / D1));
    }
}

extern "C" void kernel_launch(void* const* d_in, const int* in_sizes, int n_in,
                              void* d_out, int out_size, void* d_ws, size_t ws_size,
                              hipStream_t stream) {
    const float* x       = (const float*)d_in[0];
    const float* W       = (const float*)d_in[1];
    const float* att_src = (const float*)d_in[2];
    const float* att_dst = (const float*)d_in[3];
    const float* bias    = (const float*)d_in[4];
    const int*   ei      = (const int*)d_in[5];
    float* out = (float*)d_out;

    char* ws = (char*)d_ws;
    unsigned*       hbuf   = (unsigned*)(ws + OFF_HBUF);
    float2*         asrc   = (float2*)(ws + OFF_ASRC);
    float2*         adst   = (float2*)(ws + OFF_ADST);
    int*            gbc    = (int*)(ws + OFF_GBC);
    int*            bbase  = (int*)(ws + OFF_BBASE);
    int*            off    = (int*)(ws + OFF_OFF);
    unsigned short* srcs16 = (unsigned short*)(ws + OFF_SRC16);
    unsigned*       wpk    = (unsigned*)(ws + OFF_WPK);
    unsigned*       binb   = (unsigned*)(ws + OFF_BINB);

    k_proj<<<(NN + 63) / 64, 256, 0, stream>>>(x, W, att_src, att_dst, hbuf,
                                               asrc, adst, gbc);
    k_binA<<<(ETOT + EPB - 1) / EPB, 256, 0, stream>>>(ei, gbc, binb);
    k_bscan<<<1, 256, 0, stream>>>(gbc, bbase, off + NN);
    k_binB<<<NBK, BTH, 0, stream>>>(binb, gbc, bbase, asrc, adst, off, srcs16, wpk);
    k_agg<<<(NN * 64 + 255) / 256, 256, 0, stream>>>(off, srcs16, wpk,
                                                     (const uint2*)hbuf,
                                                     (const float2*)bias,
                                                     (float2*)out);
}